// Round 16
// baseline (2166.034 us; speedup 1.0000x reference)
//
#include <hip/hip_runtime.h>
#include <stdint.h>

// ---------- types / helpers ----------
typedef __attribute__((ext_vector_type(4))) float f32x4;
typedef __attribute__((ext_vector_type(8))) short s16x8;
typedef __attribute__((ext_vector_type(4))) unsigned short us4;

__device__ __forceinline__ float b2f(unsigned short h) {
    union { unsigned int u; float f; } v; v.u = ((unsigned int)h) << 16; return v.f;
}
__device__ __forceinline__ unsigned short f2b(float f) {
    union { float f; unsigned int u; } v; v.f = f;
    unsigned int u = v.u;
    unsigned int r = (u + 0x7FFFu + ((u >> 16) & 1u)) >> 16;
    return (unsigned short)r;
}
__device__ __forceinline__ f32x4 mfma_bf16(s16x8 a, s16x8 b, f32x4 c) {
    return __builtin_amdgcn_mfma_f32_16x16x32_bf16(a, b, c, 0, 0, 0);
}
// Fast reciprocal: v_rcp_f32 (~1 ulp) instead of the IEEE div sequence.
// R11: this alone was lstm 2174->1552us. Error budget ~1e-2, rcp err ~1e-7.
__device__ __forceinline__ float fast_rcp(float x) {
    return __builtin_amdgcn_rcpf(x);
}
__device__ __forceinline__ float sigm(float x) {
    return fast_rcp(1.f + __expf(-x));
}
__device__ __forceinline__ float tanh_ap(float x) {
    float e = __expf(2.f * x);
    return 1.f - 2.f * fast_rcp(e + 1.f);
}
__device__ __forceinline__ unsigned int mapf(float f) {   // order-preserving f32->u32
    union { float f; unsigned int u; } v; v.f = f;
    return (v.u & 0x80000000u) ? ~v.u : (v.u | 0x80000000u);
}

// Problem constants
#define TT 512
#define BB 64
#define EE 300
#define EPAD 320
#define HH 256
#define G4 1024
#define TP 520   // padded time for conv windows

// ---------- merged prep: weight conversions + conv weights + pool init + A gather ----
// Ranges: [0,1181696) prep_w | [1181696,3540992) wcat | [3540992,3573760) pool_init
//         [3573760,6195200) build_A
__global__ void prep_all(const float* __restrict__ Wih_f, const float* __restrict__ Wih_b,
                         const float* __restrict__ Whh_f, const float* __restrict__ Whh_b,
                         const float* __restrict__ bih_f, const float* __restrict__ bhh_f,
                         const float* __restrict__ bih_b, const float* __restrict__ bhh_b,
                         const float* __restrict__ w3, const float* __restrict__ w5,
                         const float* __restrict__ w7, const float* __restrict__ w9,
                         const int* __restrict__ tokens, const int* __restrict__ lengths,
                         const float* __restrict__ emb,
                         unsigned short* __restrict__ Wb_f, unsigned short* __restrict__ Wb_b,
                         unsigned short* __restrict__ Whhb_f, unsigned short* __restrict__ Whhb_b,
                         float* __restrict__ bias_f, float* __restrict__ bias_b,
                         unsigned short* __restrict__ Wcat, unsigned int* __restrict__ pooled,
                         unsigned short* __restrict__ A_f, unsigned short* __restrict__ A_b)
{
    int idx = blockIdx.x * 256 + threadIdx.x;
    if (idx < 327680) {
        int n = idx / EPAD, k = idx % EPAD;
        Wb_f[idx] = f2b(k < EE ? Wih_f[n * EE + k] : 0.f);
    } else if (idx < 655360) {
        int i = idx - 327680; int n = i / EPAD, k = i % EPAD;
        Wb_b[i] = f2b(k < EE ? Wih_b[n * EE + k] : 0.f);
    } else if (idx < 917504) {
        int i = idx - 655360; Whhb_f[i] = f2b(Whh_f[i]);
    } else if (idx < 1179648) {
        int i = idx - 917504; Whhb_b[i] = f2b(Whh_b[i]);
    } else if (idx < 1180672) {
        int i = idx - 1179648; bias_f[i] = bih_f[i] + bhh_f[i];
    } else if (idx < 1181696) {
        int i = idx - 1180672; bias_b[i] = bih_b[i] + bhh_b[i];
    } else if (idx < 3540992) {
        int i = idx - 1181696;
        int f = i / 4608, kk = i - f * 4608;
        int j = kk >> 9, cc = kk & 511;
        int g = f >> 7, fl = f & 127;
        int kw = 3 + 2 * g;
        const float* src = (g == 0) ? w3 : ((g == 1) ? w5 : ((g == 2) ? w7 : w9));
        float v = (j < kw) ? src[((size_t)fl * 512 + cc) * kw + j] : 0.f;
        Wcat[i] = f2b(v);
    } else if (idx < 3573760) {
        pooled[idx - 3540992] = 0x007FFFFFu;   // mapf(-inf)
    } else if (idx < 6195200) {
        int i = idx - 3573760;
        const int per = 32768 * 40;
        int dirc = i >= per;
        int rem = dirc ? i - per : i;
        int row = rem / 40, kc = (rem - row * 40) * 8;
        int t = row >> 6, b = row & 63;
        int ts = t;
        if (dirc) { int len = lengths[b]; ts = (t < len) ? (len - 1 - t) : t; }
        int tok = tokens[b * TT + ts];
        const float* ep = emb + (size_t)tok * EE;
        unsigned short* dst = (dirc ? A_b : A_f) + (size_t)row * EPAD + kc;
#pragma unroll
        for (int j2 = 0; j2 < 8; ++j2) {
            int e = kc + j2;
            dst[j2] = f2b(e < EE ? ep[e] : 0.f);
        }
    }
}

__global__ void zero_r(unsigned short* __restrict__ r) {
    int idx = blockIdx.x * 256 + threadIdx.x;   // 64 batches * 8 rows * 512 ch
    if (idx >= 64 * 8 * 512) return;
    int b = idx >> 12;
    int rem = idx & 4095;
    r[((size_t)b * TP + 512) * 512 + rem] = 0;
}

// ---------- GEMM: xg = A[M,320] * B[1024,320]^T(K-major) + bias -> bf16 ----------
// Output layout: xg[t][grp4][col1024][b16] (us4 packed over batch) for coalesced lstm reads
__global__ __launch_bounds__(256) void gemm_xg_k(
    const unsigned short* __restrict__ A, const unsigned short* __restrict__ Bw,
    const float* __restrict__ bias, unsigned short* __restrict__ C)
{
    __shared__ unsigned short As[128][72];
    __shared__ unsigned short Bs[128][72];
    const int KA = EPAD;
    int tid = threadIdx.x;
    int row0 = blockIdx.x * 128, col0 = blockIdx.y * 128;
    int lane = tid & 63, wave = tid >> 6;
    int wr = (wave >> 1) * 64, wc = (wave & 1) * 64;
    int l15 = lane & 15, lg = lane >> 4;
    f32x4 acc[4][4] = {};
    for (int k0 = 0; k0 < KA; k0 += 64) {
        for (int ci = tid; ci < 1024; ci += 256) {
            int rr = ci >> 3, kc = (ci & 7) * 8;
            *(s16x8*)(&As[rr][kc]) = *(const s16x8*)(A + (size_t)(row0 + rr) * KA + k0 + kc);
            *(s16x8*)(&Bs[rr][kc]) = *(const s16x8*)(Bw + (size_t)(col0 + rr) * KA + k0 + kc);
        }
        __syncthreads();
#pragma unroll
        for (int kk = 0; kk < 64; kk += 32) {
            s16x8 af[4], bf[4];
#pragma unroll
            for (int m = 0; m < 4; ++m) af[m] = *(const s16x8*)(&As[wr + m * 16 + l15][kk + lg * 8]);
#pragma unroll
            for (int n = 0; n < 4; ++n) bf[n] = *(const s16x8*)(&Bs[wc + n * 16 + l15][kk + lg * 8]);
#pragma unroll
            for (int m = 0; m < 4; ++m)
#pragma unroll
                for (int n = 0; n < 4; ++n)
                    acc[m][n] = mfma_bf16(af[m], bf[n], acc[m][n]);
        }
        __syncthreads();
    }
    // epilogue: rows are (t*64 + batch); within this tile batch = m*16 + lg*4 + i, grp = m
    int t = (row0 + wr) >> 6;
#pragma unroll
    for (int m = 0; m < 4; ++m)
#pragma unroll
        for (int n = 0; n < 4; ++n) {
            int ccol = col0 + wc + n * 16 + l15;
            float bb = bias[ccol];
            us4 pk;
#pragma unroll
            for (int i = 0; i < 4; ++i) pk[i] = f2b(acc[m][n][i] + bb);
            size_t us4_idx = (((size_t)t * 4 + m) * 1024 + ccol) * 4 + lg;
            *(us4*)(C + us4_idx * 4) = pk;
        }
}

// ---------- LSTM recurrence: persistent; ONE barrier/step via h_a double-buffer ----
// R12 anchor schedule.  R16 change: epilogue VALU reduction — running hs pointers
// (+-32768/step, no per-store address mul or len_s LDS read), unconditional fwd
// stores (t>=len garbage is finite and masked by attn scale 0), i-outer loop.
#define LSTM_STEP(S, XCUR, XNXT, HC, HW)                                          \
{                                                                                 \
    f32x4 acc[8];                                                                 \
    _Pragma("unroll")                                                             \
    for (int ct = 0; ct < 8; ++ct) {                                              \
        f32x4 a;                                                                  \
        _Pragma("unroll")                                                         \
        for (int i = 0; i < 4; ++i) a[i] = b2f(XCUR[ct][i]);                      \
        acc[ct] = a;                                                              \
    }                                                                             \
    __syncthreads();   /* single barrier: prev-step h writes visible */           \
    _Pragma("unroll")                                                             \
    for (int ct = 0; ct < 8; ++ct)                                                \
        wl2a[ct] = *(const s16x8*)(wbase + coff[ct] + 6 * 32);                    \
    s16x8 af[8];                                                                  \
    _Pragma("unroll")                                                             \
    for (int kt = 0; kt < 8; ++kt) af[kt] = *(const s16x8*)((HC) + kt * 32);      \
    _Pragma("unroll")                                                             \
    for (int kt = 0; kt < 4; ++kt)                                                \
        _Pragma("unroll")                                                         \
        for (int ct = 0; ct < 8; ++ct)                                            \
            acc[ct] = mfma_bf16(af[kt], wreg[ct * 4 + kt], acc[ct]);              \
    _Pragma("unroll")                                                             \
    for (int ct = 0; ct < 8; ++ct)                                                \
        wl2b[ct] = *(const s16x8*)(wbase + coff[ct] + 7 * 32);                    \
    _Pragma("unroll")                                                             \
    for (int ktl = 0; ktl < 2; ++ktl)                                             \
        _Pragma("unroll")                                                         \
        for (int ct = 0; ct < 8; ++ct)                                            \
            acc[ct] = mfma_bf16(af[4 + ktl], w_lds[wave][ktl][ct][lane], acc[ct]);\
    {                                                                             \
        int sp1 = (S) + 1; if (sp1 > 511) sp1 = 511;                              \
        const unsigned short* xs = xbase + (size_t)sp1 * 65536;                   \
        XNXT[0] = *(const us4*)(xs);                                              \
        XNXT[1] = *(const us4*)(xs + 256);                                        \
        XNXT[2] = *(const us4*)(xs + 4096);                                       \
        XNXT[3] = *(const us4*)(xs + 4352);                                       \
        XNXT[4] = *(const us4*)(xs + 8192);                                       \
        XNXT[5] = *(const us4*)(xs + 8448);                                       \
        XNXT[6] = *(const us4*)(xs + 12288);                                      \
        XNXT[7] = *(const us4*)(xs + 12544);                                      \
    }                                                                             \
    _Pragma("unroll")                                                             \
    for (int ct = 0; ct < 8; ++ct) acc[ct] = mfma_bf16(af[6], wl2a[ct], acc[ct]); \
    _Pragma("unroll")                                                             \
    for (int ct = 0; ct < 8; ++ct) acc[ct] = mfma_bf16(af[7], wl2b[ct], acc[ct]); \
    _Pragma("unroll")                                                             \
    for (int i = 0; i < 4; ++i) {                                                 \
        int bi = lg4 + i;                                                         \
        float hh0, hh1;                                                           \
        {                                                                         \
            float gi = acc[0][i], gf = acc[2][i], gg = acc[4][i], go = acc[6][i]; \
            float si = sigm(gi), sf = sigm(gf), so = sigm(go);                    \
            float tg = tanh_ap(gg);                                               \
            float cc = sf * c[i] + si * tg; c[i] = cc;                            \
            hh0 = so * tanh_ap(cc);                                               \
        }                                                                         \
        {                                                                         \
            float gi = acc[1][i], gf = acc[3][i], gg = acc[5][i], go = acc[7][i]; \
            float si = sigm(gi), sf = sigm(gf), so = sigm(go);                    \
            float tg = tanh_ap(gg);                                               \
            float cc = sf * c[4 + i] + si * tg; c[4 + i] = cc;                    \
            hh1 = so * tanh_ap(cc);                                               \
        }                                                                         \
        unsigned short p0 = f2b(hh0), p1 = f2b(hh1);                              \
        (HW)[bi][ucol] = p0;                                                      \
        (HW)[bi][ucol + 16] = p1;                                                 \
        if (dir == 0 || (S) < mylen[i]) {                                         \
            hsp[i][0] = p0;                                                       \
            hsp[i][16] = p1;                                                      \
        }                                                                         \
        hsp[i] += hs_step;                                                        \
    }                                                                             \
}

__global__ __launch_bounds__(512, 2) void lstm_rec(
    const unsigned short* __restrict__ xg_f, const unsigned short* __restrict__ xg_b,
    const unsigned short* __restrict__ Whh_fb, const unsigned short* __restrict__ Whh_bb,
    const int* __restrict__ lengths, unsigned short* __restrict__ hs)
{
    int wg = blockIdx.x;
    int dir = wg >> 2, grp = wg & 3;
    const unsigned short* XG = dir ? xg_b : xg_f;     // [t][grp][1024 col][16 b]
    const unsigned short* WH = dir ? Whh_bb : Whh_fb; // [1024 col][256 k]
    int tid = threadIdx.x, lane = tid & 63, wave = tid >> 6;
    int l15 = lane & 15, lg = lane >> 4;
    int lg4 = lg * 4;
    int ucol = wave * 32 + l15;                       // h2=0 column; h2=1 at +16

    __shared__ unsigned short h_a[2][16][264];   // DOUBLE-buffered hidden state
    __shared__ s16x8 w_lds[8][2][8][64];         // kt4-5, per-wave private, 128 KB
    __shared__ int len_s[16];
    __shared__ int ml_s;

    if (tid < 16) len_s[tid] = lengths[grp * 16 + tid];
    for (int i = tid; i < 2 * 16 * 264; i += 512) (&h_a[0][0][0])[i] = 0;
    __syncthreads();
    if (tid == 0) {
        int m = 0;
        for (int i = 0; i < 16; ++i) m = max(m, len_s[i]);
        ml_s = m;
    }

    // per-thread weight base + per-ct col offsets (units: unsigned short)
    const unsigned short* wbase = WH + (size_t)(wave * 32 + l15) * HH + lg * 8;
    const int coff[8] = {0, 16 * HH, 256 * HH, 272 * HH, 512 * HH, 528 * HH, 768 * HH, 784 * HH};

    // persistent weights: kt0-3 regs, kt4-5 LDS
    s16x8 wreg[32];
#pragma unroll
    for (int ct = 0; ct < 8; ++ct) {
#pragma unroll
        for (int kt = 0; kt < 4; ++kt)
            wreg[ct * 4 + kt] = *(const s16x8*)(wbase + coff[ct] + kt * 32);
#pragma unroll
        for (int ktl = 0; ktl < 2; ++ktl)
            w_lds[wave][ktl][ct][lane] = *(const s16x8*)(wbase + coff[ct] + (4 + ktl) * 32);
    }
    __syncthreads();   // w_lds + ml_s + len_s ready
    int maxlen = ml_s;

    // per-thread lengths + running hs store pointers (running, +-32768 us/step)
    int mylen[4];
    unsigned short* hsp[4];
    const int hs_step = dir ? -32768 : 32768;
#pragma unroll
    for (int i = 0; i < 4; ++i) {
        mylen[i] = len_s[lg4 + i];
        size_t cbase = (size_t)(grp * 16 + lg4 + i) * 512 + dir * 256 + ucol;
        int t0 = dir ? (mylen[i] - 1) : 0;
        hsp[i] = hs + (size_t)t0 * 32768 + cbase;
    }

    float c[8];
#pragma unroll
    for (int q = 0; q < 8; ++q) c[q] = 0.f;

    const unsigned short* hc0 = &h_a[0][l15][lg * 8];
    const unsigned short* hc1 = &h_a[1][l15][lg * 8];
    // xg base for this thread (us units); per-s stride 65536
    const unsigned short* xbase = XG + (size_t)grp * 16384 + (wave * 32 + l15) * 16 + lg * 4;

    s16x8 wl2a[8], wl2b[8];
    us4 xga[8], xgb[8];
    {
        const unsigned short* xs = xbase;
        xga[0] = *(const us4*)(xs);         xga[1] = *(const us4*)(xs + 256);
        xga[2] = *(const us4*)(xs + 4096);  xga[3] = *(const us4*)(xs + 4352);
        xga[4] = *(const us4*)(xs + 8192);  xga[5] = *(const us4*)(xs + 8448);
        xga[6] = *(const us4*)(xs + 12288); xga[7] = *(const us4*)(xs + 12544);
    }

    int s = 0;
    for (; s + 1 < maxlen; s += 2) {
        LSTM_STEP(s, xga, xgb, hc0, h_a[1])
        LSTM_STEP(s + 1, xgb, xga, hc1, h_a[0])
    }
    if (s < maxlen) {
        LSTM_STEP(s, xga, xgb, hc0, h_a[1])
    }
}

// ---------- attention part 1: per-(b,t) softmax scale -> scale_ws ----------
__global__ __launch_bounds__(256) void attn_e(
    const unsigned short* __restrict__ hs, const int* __restrict__ lengths,
    const float* __restrict__ attn_w, float* __restrict__ scale_ws)
{
    int b = blockIdx.x, tid = threadIdx.x;
    __shared__ float aw[512];
    __shared__ float e_s[512];
    __shared__ float red[4];
    __shared__ float ssum;
    for (int i = tid; i < 512; i += 256) aw[i] = attn_w[i];
    int len = lengths[b];
    __syncthreads();
    for (int t = tid; t < 512; t += 256) {
        float e = 0.f;
        if (t < len) {
            const unsigned short* hp = hs + ((size_t)t * 64 + b) * 512;
            float u = 0.f;
            for (int c8 = 0; c8 < 64; ++c8) {
                s16x8 hv = *(const s16x8*)(hp + c8 * 8);
#pragma unroll
                for (int j = 0; j < 8; ++j)
                    u += tanh_ap(b2f((unsigned short)hv[j])) * aw[c8 * 8 + j];
            }
            e = __expf(u);   // attn_b cancels in normalization
        }
        e_s[t] = e;
    }
    __syncthreads();
    float p = e_s[tid] + e_s[tid + 256];
#pragma unroll
    for (int o = 32; o > 0; o >>= 1) p += __shfl_down(p, o);
    if ((tid & 63) == 0) red[tid >> 6] = p;
    __syncthreads();
    if (tid == 0) ssum = red[0] + red[1] + red[2] + red[3];
    __syncthreads();
    float inv = fast_rcp(ssum);
    for (int t = tid; t < 512; t += 256)
        scale_ws[b * 512 + t] = e_s[t] * inv;
}

// ---------- attention part 2: r[b][t][c] = hs[t][b][c] * scale (coalesced) ------
// One wave per (b,t) row; 8192 blocks x 4 waves = 32768 rows.
__global__ __launch_bounds__(256) void attn_scale(
    const unsigned short* __restrict__ hs, const float* __restrict__ scale_ws,
    unsigned short* __restrict__ r)
{
    int row = blockIdx.x * 4 + (threadIdx.x >> 6);   // b*512 + t
    int lane = threadIdx.x & 63;
    int b = row >> 9, t = row & 511;
    float sc = scale_ws[row];
    s16x8 hv = *(const s16x8*)(hs + ((size_t)t * 64 + b) * 512 + lane * 8);
    s16x8 ov;
#pragma unroll
    for (int j = 0; j < 8; ++j)
        ov[j] = (short)f2b(b2f((unsigned short)hv[j]) * sc);
    *(s16x8*)(r + ((size_t)b * TP + t) * 512 + lane * 8) = ov;
}

// ---------- conv as implicit-im2col GEMM + fused max-pool ----------
// K-trimmed: filter group g = blockIdx.y has kernel width 3+2g -> only
// (3+2g)*512 of the 4608 K entries are nonzero (Wcat zero-padded beyond).
__global__ __launch_bounds__(256) void gemm_conv(
    const unsigned short* __restrict__ R, const unsigned short* __restrict__ W,
    unsigned int* __restrict__ pooled)
{
    __shared__ unsigned short As[128][72];
    __shared__ unsigned short Bs[128][72];
    int tid = threadIdx.x;
    int bm = blockIdx.x;          // 0..255
    int b = bm >> 2;
    int t0 = (bm & 3) * 128;
    int col0 = blockIdx.y * 128;  // group g = blockIdx.y
    int kmax = (3 + 2 * (int)blockIdx.y) * 512;   // 1536/2560/3584/4608
    int lane = tid & 63, wave = tid >> 6;
    int wr = (wave >> 1) * 64, wc = (wave & 1) * 64;
    int l15 = lane & 15, lg = lane >> 4;
    f32x4 acc[4][4] = {};
    for (int k0 = 0; k0 < kmax; k0 += 64) {
        int j = k0 >> 9, c0 = k0 & 511;  // 64 | 512 so tap j constant per chunk
        for (int ci = tid; ci < 1024; ci += 256) {
            int rr = ci >> 3, kc = (ci & 7) * 8;
            *(s16x8*)(&As[rr][kc]) =
                *(const s16x8*)(R + ((size_t)(b * TP) + t0 + rr + j) * 512 + c0 + kc);
            *(s16x8*)(&Bs[rr][kc]) = *(const s16x8*)(W + (size_t)(col0 + rr) * 4608 + k0 + kc);
        }
        __syncthreads();
#pragma unroll
        for (int kk = 0; kk < 64; kk += 32) {
            s16x8 af[4], bf[4];
#pragma unroll
            for (int m = 0; m < 4; ++m) af[m] = *(const s16x8*)(&As[wr + m * 16 + l15][kk + lg * 8]);
#pragma unroll
            for (int n = 0; n < 4; ++n) bf[n] = *(const s16x8*)(&Bs[wc + n * 16 + l15][kk + lg * 8]);
#pragma unroll
            for (int m = 0; m < 4; ++m)
#pragma unroll
                for (int n = 0; n < 4; ++n)
                    acc[m][n] = mfma_bf16(af[m], bf[n], acc[m][n]);
        }
        __syncthreads();
    }
    // fused max-pool epilogue (bias added later; max is monotone)
#pragma unroll
    for (int m = 0; m < 4; ++m)
#pragma unroll
        for (int n = 0; n < 4; ++n) {
            int f = col0 + wc + n * 16 + l15;
            int g = f >> 7;
            int tmax = 509 - 2 * g;   // valid t <= 512 - k_g
            float v = -3.4e38f;
            int tb = t0 + wr + m * 16 + lg * 4;
#pragma unroll
            for (int i = 0; i < 4; ++i) {
                int t = tb + i;
                if (t <= tmax) v = fmaxf(v, acc[m][n][i]);
            }
            v = fmaxf(v, __shfl_xor(v, 16));
            v = fmaxf(v, __shfl_xor(v, 32));
            if (lane < 16) atomicMax(&pooled[b * 512 + f], mapf(v));
        }
}

// ---------- pooled -> fc1 -> fc2 -> sigmoid ----------
__global__ __launch_bounds__(256) void fc_k(
    const unsigned int* __restrict__ pooled,
    const float* __restrict__ cb3, const float* __restrict__ cb5,
    const float* __restrict__ cb7, const float* __restrict__ cb9,
    const float* __restrict__ fc1_w, const float* __restrict__ fc1_b,
    const float* __restrict__ fc2_w, const float* __restrict__ fc2_b,
    float* __restrict__ out)
{
    int b = blockIdx.x, tid = threadIdx.x;
    __shared__ float x[512];
    __shared__ float y[256];
    for (int i = tid; i < 512; i += 256) {
        unsigned int u = pooled[b * 512 + i];
        unsigned int bits = (u & 0x80000000u) ? (u & 0x7FFFFFFFu) : ~u;
        union { unsigned int uu; float f; } v; v.uu = bits;
        int g = i >> 7;
        const float* cb = (g == 0) ? cb3 : ((g == 1) ? cb5 : ((g == 2) ? cb7 : cb9));
        x[i] = v.f + cb[i & 127];
    }
    __syncthreads();
    float a = fc1_b[tid];
    const float* wrow = fc1_w + (size_t)tid * 512;
    for (int k = 0; k < 512; k += 4)
        a += x[k] * wrow[k] + x[k + 1] * wrow[k + 1] + x[k + 2] * wrow[k + 2] + x[k + 3] * wrow[k + 3];
    y[tid] = fmaxf(a, 0.f);
    __syncthreads();
    if (tid < 64) {
        float p = 0.f;
        for (int k = tid; k < 256; k += 64) p += y[k] * fc2_w[k];
#pragma unroll
        for (int o = 32; o > 0; o >>= 1) p += __shfl_down(p, o);
        if (tid == 0) out[b] = 1.f / (1.f + __expf(-(p + fc2_b[0])));
    }
}

// ---------- host ----------
extern "C" void kernel_launch(void* const* d_in, const int* in_sizes, int n_in,
                              void* d_out, int out_size, void* d_ws, size_t ws_size,
                              hipStream_t stream)
{
    const int*   tokens  = (const int*)d_in[0];
    const int*   lengths = (const int*)d_in[1];
    const float* emb     = (const float*)d_in[2];
    const float* Wih_f   = (const float*)d_in[3];
    const float* Whh_f   = (const float*)d_in[4];
    const float* bih_f   = (const float*)d_in[5];
    const float* bhh_f   = (const float*)d_in[6];
    const float* Wih_b   = (const float*)d_in[7];
    const float* Whh_b   = (const float*)d_in[8];
    const float* bih_b   = (const float*)d_in[9];
    const float* bhh_b   = (const float*)d_in[10];
    const float* attn_w  = (const float*)d_in[11];
    const float* cw3 = (const float*)d_in[13]; const float* cb3 = (const float*)d_in[14];
    const float* cw5 = (const float*)d_in[15]; const float* cb5 = (const float*)d_in[16];
    const float* cw7 = (const float*)d_in[17]; const float* cb7 = (const float*)d_in[18];
    const float* cw9 = (const float*)d_in[19]; const float* cb9 = (const float*)d_in[20];
    const float* fc1_w = (const float*)d_in[21]; const float* fc1_b = (const float*)d_in[22];
    const float* fc2_w = (const float*)d_in[23]; const float* fc2_b = (const float*)d_in[24];
    float* out = (float*)d_out;

    char* ws = (char*)d_ws;
    // Workspace layout (~217 MB). r reuses A_f/A_b (A dead after xg GEMMs);
    // scale_ws reuses Wb_f (dead after xg GEMMs).
    unsigned short* A_f    = (unsigned short*)(ws + 0);
    unsigned short* A_b    = (unsigned short*)(ws + 20971520);
    unsigned short* r      = (unsigned short*)(ws + 0);           // overlaps A (time-disjoint)
    unsigned short* Wb_f   = (unsigned short*)(ws + 41943040);
    float*          scale_ws = (float*)(ws + 41943040);           // overlaps Wb_f (time-disjoint)
    unsigned short* Wb_b   = (unsigned short*)(ws + 42598400);
    unsigned short* Whhb_f = (unsigned short*)(ws + 43253760);
    unsigned short* Whhb_b = (unsigned short*)(ws + 43778048);
    float*          bias_f = (float*)(ws + 44302336);
    float*          bias_b = (float*)(ws + 44306432);
    unsigned short* Wcat   = (unsigned short*)(ws + 44310528);
    unsigned int*   pooled = (unsigned int*)(ws + 49029120);
    unsigned short* xg_f   = (unsigned short*)(ws + 49160192);
    unsigned short* xg_b   = (unsigned short*)(ws + 116269056);
    unsigned short* hs     = (unsigned short*)(ws + 183377920);
    // total = 216932352 bytes

    prep_all<<<(6195200 + 255) / 256, 256, 0, stream>>>(
        Wih_f, Wih_b, Whh_f, Whh_b, bih_f, bhh_f, bih_b, bhh_b,
        cw3, cw5, cw7, cw9, tokens, lengths, emb,
        Wb_f, Wb_b, Whhb_f, Whhb_b, bias_f, bias_b, Wcat, pooled, A_f, A_b);

    gemm_xg_k<<<dim3(256, 8), 256, 0, stream>>>(A_f, Wb_f, bias_f, xg_f);
    gemm_xg_k<<<dim3(256, 8), 256, 0, stream>>>(A_b, Wb_b, bias_b, xg_b);

    lstm_rec<<<8, 512, 0, stream>>>(xg_f, xg_b, Whhb_f, Whhb_b, lengths, hs);

    zero_r<<<(262144 + 255) / 256, 256, 0, stream>>>(r);   // after GEMMs (r overlaps A)
    attn_e<<<64, 256, 0, stream>>>(hs, lengths, attn_w, scale_ws);
    attn_scale<<<8192, 256, 0, stream>>>(hs, scale_ws, r);

    gemm_conv<<<dim3(256, 4), 256, 0, stream>>>(r, Wcat, pooled);

    fc_k<<<64, 256, 0, stream>>>(pooled, cb3, cb5, cb7, cb9,
                                 fc1_w, fc1_b, fc2_w, fc2_b, out);
}

// Round 17
// 1896.377 us; speedup vs baseline: 1.1422x; 1.1422x over previous
//
#include <hip/hip_runtime.h>
#include <stdint.h>

// ---------- types / helpers ----------
typedef __attribute__((ext_vector_type(4))) float f32x4;
typedef __attribute__((ext_vector_type(8))) short s16x8;
typedef __attribute__((ext_vector_type(4))) unsigned short us4;

__device__ __forceinline__ float b2f(unsigned short h) {
    union { unsigned int u; float f; } v; v.u = ((unsigned int)h) << 16; return v.f;
}
__device__ __forceinline__ unsigned short f2b(float f) {
    union { float f; unsigned int u; } v; v.f = f;
    unsigned int u = v.u;
    unsigned int r = (u + 0x7FFFu + ((u >> 16) & 1u)) >> 16;
    return (unsigned short)r;
}
__device__ __forceinline__ f32x4 mfma_bf16(s16x8 a, s16x8 b, f32x4 c) {
    return __builtin_amdgcn_mfma_f32_16x16x32_bf16(a, b, c, 0, 0, 0);
}
// Fast reciprocal: v_rcp_f32 (~1 ulp) instead of the IEEE div sequence.
// R11: this alone was lstm 2174->1552us. Error budget ~1e-2, rcp err ~1e-7.
__device__ __forceinline__ float fast_rcp(float x) {
    return __builtin_amdgcn_rcpf(x);
}
__device__ __forceinline__ float sigm(float x) {
    return fast_rcp(1.f + __expf(-x));
}
__device__ __forceinline__ float tanh_ap(float x) {
    float e = __expf(2.f * x);
    return 1.f - 2.f * fast_rcp(e + 1.f);
}
__device__ __forceinline__ unsigned int mapf(float f) {   // order-preserving f32->u32
    union { float f; unsigned int u; } v; v.f = f;
    return (v.u & 0x80000000u) ? ~v.u : (v.u | 0x80000000u);
}

// Problem constants
#define TT 512
#define BB 64
#define EE 300
#define EPAD 320
#define HH 256
#define G4 1024
#define TP 520   // padded time for conv windows

// ---------- merged prep: weight conversions + conv weights + pool init + A gather ----
// Ranges: [0,1181696) prep_w | [1181696,3540992) wcat | [3540992,3573760) pool_init
//         [3573760,6195200) build_A
__global__ void prep_all(const float* __restrict__ Wih_f, const float* __restrict__ Wih_b,
                         const float* __restrict__ Whh_f, const float* __restrict__ Whh_b,
                         const float* __restrict__ bih_f, const float* __restrict__ bhh_f,
                         const float* __restrict__ bih_b, const float* __restrict__ bhh_b,
                         const float* __restrict__ w3, const float* __restrict__ w5,
                         const float* __restrict__ w7, const float* __restrict__ w9,
                         const int* __restrict__ tokens, const int* __restrict__ lengths,
                         const float* __restrict__ emb,
                         unsigned short* __restrict__ Wb_f, unsigned short* __restrict__ Wb_b,
                         unsigned short* __restrict__ Whhb_f, unsigned short* __restrict__ Whhb_b,
                         float* __restrict__ bias_f, float* __restrict__ bias_b,
                         unsigned short* __restrict__ Wcat, unsigned int* __restrict__ pooled,
                         unsigned short* __restrict__ A_f, unsigned short* __restrict__ A_b)
{
    int idx = blockIdx.x * 256 + threadIdx.x;
    if (idx < 327680) {
        int n = idx / EPAD, k = idx % EPAD;
        Wb_f[idx] = f2b(k < EE ? Wih_f[n * EE + k] : 0.f);
    } else if (idx < 655360) {
        int i = idx - 327680; int n = i / EPAD, k = i % EPAD;
        Wb_b[i] = f2b(k < EE ? Wih_b[n * EE + k] : 0.f);
    } else if (idx < 917504) {
        int i = idx - 655360; Whhb_f[i] = f2b(Whh_f[i]);
    } else if (idx < 1179648) {
        int i = idx - 917504; Whhb_b[i] = f2b(Whh_b[i]);
    } else if (idx < 1180672) {
        int i = idx - 1179648; bias_f[i] = bih_f[i] + bhh_f[i];
    } else if (idx < 1181696) {
        int i = idx - 1180672; bias_b[i] = bih_b[i] + bhh_b[i];
    } else if (idx < 3540992) {
        int i = idx - 1181696;
        int f = i / 4608, kk = i - f * 4608;
        int j = kk >> 9, cc = kk & 511;
        int g = f >> 7, fl = f & 127;
        int kw = 3 + 2 * g;
        const float* src = (g == 0) ? w3 : ((g == 1) ? w5 : ((g == 2) ? w7 : w9));
        float v = (j < kw) ? src[((size_t)fl * 512 + cc) * kw + j] : 0.f;
        Wcat[i] = f2b(v);
    } else if (idx < 3573760) {
        pooled[idx - 3540992] = 0x007FFFFFu;   // mapf(-inf)
    } else if (idx < 6195200) {
        int i = idx - 3573760;
        const int per = 32768 * 40;
        int dirc = i >= per;
        int rem = dirc ? i - per : i;
        int row = rem / 40, kc = (rem - row * 40) * 8;
        int t = row >> 6, b = row & 63;
        int ts = t;
        if (dirc) { int len = lengths[b]; ts = (t < len) ? (len - 1 - t) : t; }
        int tok = tokens[b * TT + ts];
        const float* ep = emb + (size_t)tok * EE;
        unsigned short* dst = (dirc ? A_b : A_f) + (size_t)row * EPAD + kc;
#pragma unroll
        for (int j2 = 0; j2 < 8; ++j2) {
            int e = kc + j2;
            dst[j2] = f2b(e < EE ? ep[e] : 0.f);
        }
    }
}

__global__ void zero_r(unsigned short* __restrict__ r) {
    int idx = blockIdx.x * 256 + threadIdx.x;   // 64 batches * 8 rows * 512 ch
    if (idx >= 64 * 8 * 512) return;
    int b = idx >> 12;
    int rem = idx & 4095;
    r[((size_t)b * TP + 512) * 512 + rem] = 0;
}

// ---------- GEMM: xg = A[M,320] * B[1024,320]^T(K-major) + bias -> bf16 ----------
// Output layout: xg[t][grp4][col1024][b16] (us4 packed over batch) for coalesced lstm reads
__global__ __launch_bounds__(256) void gemm_xg_k(
    const unsigned short* __restrict__ A, const unsigned short* __restrict__ Bw,
    const float* __restrict__ bias, unsigned short* __restrict__ C)
{
    __shared__ unsigned short As[128][72];
    __shared__ unsigned short Bs[128][72];
    const int KA = EPAD;
    int tid = threadIdx.x;
    int row0 = blockIdx.x * 128, col0 = blockIdx.y * 128;
    int lane = tid & 63, wave = tid >> 6;
    int wr = (wave >> 1) * 64, wc = (wave & 1) * 64;
    int l15 = lane & 15, lg = lane >> 4;
    f32x4 acc[4][4] = {};
    for (int k0 = 0; k0 < KA; k0 += 64) {
        for (int ci = tid; ci < 1024; ci += 256) {
            int rr = ci >> 3, kc = (ci & 7) * 8;
            *(s16x8*)(&As[rr][kc]) = *(const s16x8*)(A + (size_t)(row0 + rr) * KA + k0 + kc);
            *(s16x8*)(&Bs[rr][kc]) = *(const s16x8*)(Bw + (size_t)(col0 + rr) * KA + k0 + kc);
        }
        __syncthreads();
#pragma unroll
        for (int kk = 0; kk < 64; kk += 32) {
            s16x8 af[4], bf[4];
#pragma unroll
            for (int m = 0; m < 4; ++m) af[m] = *(const s16x8*)(&As[wr + m * 16 + l15][kk + lg * 8]);
#pragma unroll
            for (int n = 0; n < 4; ++n) bf[n] = *(const s16x8*)(&Bs[wc + n * 16 + l15][kk + lg * 8]);
#pragma unroll
            for (int m = 0; m < 4; ++m)
#pragma unroll
                for (int n = 0; n < 4; ++n)
                    acc[m][n] = mfma_bf16(af[m], bf[n], acc[m][n]);
        }
        __syncthreads();
    }
    // epilogue: rows are (t*64 + batch); within this tile batch = m*16 + lg*4 + i, grp = m
    int t = (row0 + wr) >> 6;
#pragma unroll
    for (int m = 0; m < 4; ++m)
#pragma unroll
        for (int n = 0; n < 4; ++n) {
            int ccol = col0 + wc + n * 16 + l15;
            float bb = bias[ccol];
            us4 pk;
#pragma unroll
            for (int i = 0; i < 4; ++i) pk[i] = f2b(acc[m][n][i] + bb);
            size_t us4_idx = (((size_t)t * 4 + m) * 1024 + ccol) * 4 + lg;
            *(us4*)(C + us4_idx * 4) = pk;
        }
}

// ---------- LSTM recurrence: persistent; ONE barrier/step via h_a double-buffer ----
// R15 configuration (1485us anchor): R12 schedule, wl2a issued after the barrier.
// R16 lesson: epilogue rewrites (running pointers, i-outer) REGRESS — do not touch.
#define LSTM_STEP(S, XCUR, XNXT, HC, HW)                                          \
{                                                                                 \
    f32x4 acc[8];                                                                 \
    _Pragma("unroll")                                                             \
    for (int ct = 0; ct < 8; ++ct) {                                              \
        f32x4 a;                                                                  \
        _Pragma("unroll")                                                         \
        for (int i = 0; i < 4; ++i) a[i] = b2f(XCUR[ct][i]);                      \
        acc[ct] = a;                                                              \
    }                                                                             \
    __syncthreads();   /* single barrier: prev-step h writes visible */           \
    _Pragma("unroll")                                                             \
    for (int ct = 0; ct < 8; ++ct)                                                \
        wl2a[ct] = *(const s16x8*)(wbase + coff[ct] + 6 * 32);                    \
    s16x8 af[8];                                                                  \
    _Pragma("unroll")                                                             \
    for (int kt = 0; kt < 8; ++kt) af[kt] = *(const s16x8*)((HC) + kt * 32);      \
    _Pragma("unroll")                                                             \
    for (int kt = 0; kt < 4; ++kt)                                                \
        _Pragma("unroll")                                                         \
        for (int ct = 0; ct < 8; ++ct)                                            \
            acc[ct] = mfma_bf16(af[kt], wreg[ct * 4 + kt], acc[ct]);              \
    _Pragma("unroll")                                                             \
    for (int ct = 0; ct < 8; ++ct)                                                \
        wl2b[ct] = *(const s16x8*)(wbase + coff[ct] + 7 * 32);                    \
    _Pragma("unroll")                                                             \
    for (int ktl = 0; ktl < 2; ++ktl)                                             \
        _Pragma("unroll")                                                         \
        for (int ct = 0; ct < 8; ++ct)                                            \
            acc[ct] = mfma_bf16(af[4 + ktl], w_lds[wave][ktl][ct][lane], acc[ct]);\
    {                                                                             \
        int sp1 = (S) + 1; if (sp1 > 511) sp1 = 511;                              \
        const unsigned short* xs = xbase + (size_t)sp1 * 65536;                   \
        XNXT[0] = *(const us4*)(xs);                                              \
        XNXT[1] = *(const us4*)(xs + 256);                                        \
        XNXT[2] = *(const us4*)(xs + 4096);                                       \
        XNXT[3] = *(const us4*)(xs + 4352);                                       \
        XNXT[4] = *(const us4*)(xs + 8192);                                       \
        XNXT[5] = *(const us4*)(xs + 8448);                                       \
        XNXT[6] = *(const us4*)(xs + 12288);                                      \
        XNXT[7] = *(const us4*)(xs + 12544);                                      \
    }                                                                             \
    _Pragma("unroll")                                                             \
    for (int ct = 0; ct < 8; ++ct) acc[ct] = mfma_bf16(af[6], wl2a[ct], acc[ct]); \
    _Pragma("unroll")                                                             \
    for (int ct = 0; ct < 8; ++ct) acc[ct] = mfma_bf16(af[7], wl2b[ct], acc[ct]); \
    _Pragma("unroll")                                                             \
    for (int h2 = 0; h2 < 2; ++h2)                                                \
    _Pragma("unroll")                                                             \
    for (int i = 0; i < 4; ++i) {                                                 \
        int bi = lg * 4 + i;                                                      \
        int u = wave * 32 + h2 * 16 + l15;                                        \
        float gi = acc[0 + h2][i], gf = acc[2 + h2][i];                           \
        float gg = acc[4 + h2][i], go = acc[6 + h2][i];                           \
        float si = sigm(gi), sf = sigm(gf), so = sigm(go);                        \
        float tg = tanh_ap(gg);                                                   \
        int q = h2 * 4 + i;                                                       \
        float cc = sf * c[q] + si * tg; c[q] = cc;                                \
        float hh = so * tanh_ap(cc);                                              \
        (HW)[bi][u] = f2b(hh);                                                    \
        int len = len_s[bi];                                                      \
        if ((S) < len) {                                                          \
            int t_out = dir ? (len - 1 - (S)) : (S);                              \
            hs[((size_t)t_out * 64 + (grp * 16 + bi)) * 512 + dir * 256 + u] = f2b(hh); \
        }                                                                         \
    }                                                                             \
}

__global__ __launch_bounds__(512, 2) void lstm_rec(
    const unsigned short* __restrict__ xg_f, const unsigned short* __restrict__ xg_b,
    const unsigned short* __restrict__ Whh_fb, const unsigned short* __restrict__ Whh_bb,
    const int* __restrict__ lengths, unsigned short* __restrict__ hs)
{
    int wg = blockIdx.x;
    int dir = wg >> 2, grp = wg & 3;
    const unsigned short* XG = dir ? xg_b : xg_f;     // [t][grp][1024 col][16 b]
    const unsigned short* WH = dir ? Whh_bb : Whh_fb; // [1024 col][256 k]
    int tid = threadIdx.x, lane = tid & 63, wave = tid >> 6;
    int l15 = lane & 15, lg = lane >> 4;

    __shared__ unsigned short h_a[2][16][264];   // DOUBLE-buffered hidden state
    __shared__ s16x8 w_lds[8][2][8][64];         // kt4-5, per-wave private, 128 KB
    __shared__ int len_s[16];
    __shared__ int ml_s;

    if (tid < 16) len_s[tid] = lengths[grp * 16 + tid];
    for (int i = tid; i < 2 * 16 * 264; i += 512) (&h_a[0][0][0])[i] = 0;
    __syncthreads();
    if (tid == 0) {
        int m = 0;
        for (int i = 0; i < 16; ++i) m = max(m, len_s[i]);
        ml_s = m;
    }

    // per-thread weight base + per-ct col offsets (units: unsigned short)
    const unsigned short* wbase = WH + (size_t)(wave * 32 + l15) * HH + lg * 8;
    const int coff[8] = {0, 16 * HH, 256 * HH, 272 * HH, 512 * HH, 528 * HH, 768 * HH, 784 * HH};

    // persistent weights: kt0-3 regs, kt4-5 LDS
    s16x8 wreg[32];
#pragma unroll
    for (int ct = 0; ct < 8; ++ct) {
#pragma unroll
        for (int kt = 0; kt < 4; ++kt)
            wreg[ct * 4 + kt] = *(const s16x8*)(wbase + coff[ct] + kt * 32);
#pragma unroll
        for (int ktl = 0; ktl < 2; ++ktl)
            w_lds[wave][ktl][ct][lane] = *(const s16x8*)(wbase + coff[ct] + (4 + ktl) * 32);
    }
    __syncthreads();   // w_lds + ml_s ready
    int maxlen = ml_s;

    float c[8];
#pragma unroll
    for (int q = 0; q < 8; ++q) c[q] = 0.f;

    const unsigned short* hc0 = &h_a[0][l15][lg * 8];
    const unsigned short* hc1 = &h_a[1][l15][lg * 8];
    // xg base for this thread (us units); per-s stride 65536
    const unsigned short* xbase = XG + (size_t)grp * 16384 + (wave * 32 + l15) * 16 + lg * 4;

    s16x8 wl2a[8], wl2b[8];
    us4 xga[8], xgb[8];
    {
        const unsigned short* xs = xbase;
        xga[0] = *(const us4*)(xs);         xga[1] = *(const us4*)(xs + 256);
        xga[2] = *(const us4*)(xs + 4096);  xga[3] = *(const us4*)(xs + 4352);
        xga[4] = *(const us4*)(xs + 8192);  xga[5] = *(const us4*)(xs + 8448);
        xga[6] = *(const us4*)(xs + 12288); xga[7] = *(const us4*)(xs + 12544);
    }

    int s = 0;
    for (; s + 1 < maxlen; s += 2) {
        LSTM_STEP(s, xga, xgb, hc0, h_a[1])
        LSTM_STEP(s + 1, xgb, xga, hc1, h_a[0])
    }
    if (s < maxlen) {
        LSTM_STEP(s, xga, xgb, hc0, h_a[1])
    }
}

// ---------- attention part 1: per-(b,t) softmax scale -> scale_ws ----------
__global__ __launch_bounds__(256) void attn_e(
    const unsigned short* __restrict__ hs, const int* __restrict__ lengths,
    const float* __restrict__ attn_w, float* __restrict__ scale_ws)
{
    int b = blockIdx.x, tid = threadIdx.x;
    __shared__ float aw[512];
    __shared__ float e_s[512];
    __shared__ float red[4];
    __shared__ float ssum;
    for (int i = tid; i < 512; i += 256) aw[i] = attn_w[i];
    int len = lengths[b];
    __syncthreads();
    for (int t = tid; t < 512; t += 256) {
        float e = 0.f;
        if (t < len) {
            const unsigned short* hp = hs + ((size_t)t * 64 + b) * 512;
            float u = 0.f;
            for (int c8 = 0; c8 < 64; ++c8) {
                s16x8 hv = *(const s16x8*)(hp + c8 * 8);
#pragma unroll
                for (int j = 0; j < 8; ++j)
                    u += tanh_ap(b2f((unsigned short)hv[j])) * aw[c8 * 8 + j];
            }
            e = __expf(u);   // attn_b cancels in normalization
        }
        e_s[t] = e;
    }
    __syncthreads();
    float p = e_s[tid] + e_s[tid + 256];
#pragma unroll
    for (int o = 32; o > 0; o >>= 1) p += __shfl_down(p, o);
    if ((tid & 63) == 0) red[tid >> 6] = p;
    __syncthreads();
    if (tid == 0) ssum = red[0] + red[1] + red[2] + red[3];
    __syncthreads();
    float inv = fast_rcp(ssum);
    for (int t = tid; t < 512; t += 256)
        scale_ws[b * 512 + t] = e_s[t] * inv;
}

// ---------- attention part 2: r[b][t][c] = hs[t][b][c] * scale (coalesced) ------
// One wave per (b,t) row; 8192 blocks x 4 waves = 32768 rows.
__global__ __launch_bounds__(256) void attn_scale(
    const unsigned short* __restrict__ hs, const float* __restrict__ scale_ws,
    unsigned short* __restrict__ r)
{
    int row = blockIdx.x * 4 + (threadIdx.x >> 6);   // b*512 + t
    int lane = threadIdx.x & 63;
    int b = row >> 9, t = row & 511;
    float sc = scale_ws[row];
    s16x8 hv = *(const s16x8*)(hs + ((size_t)t * 64 + b) * 512 + lane * 8);
    s16x8 ov;
#pragma unroll
    for (int j = 0; j < 8; ++j)
        ov[j] = (short)f2b(b2f((unsigned short)hv[j]) * sc);
    *(s16x8*)(r + ((size_t)b * TP + t) * 512 + lane * 8) = ov;
}

// ---------- conv as implicit-im2col GEMM + fused max-pool ----------
// K-trimmed: filter group g = blockIdx.y has kernel width 3+2g -> only
// (3+2g)*512 of the 4608 K entries are nonzero (Wcat zero-padded beyond).
__global__ __launch_bounds__(256) void gemm_conv(
    const unsigned short* __restrict__ R, const unsigned short* __restrict__ W,
    unsigned int* __restrict__ pooled)
{
    __shared__ unsigned short As[128][72];
    __shared__ unsigned short Bs[128][72];
    int tid = threadIdx.x;
    int bm = blockIdx.x;          // 0..255
    int b = bm >> 2;
    int t0 = (bm & 3) * 128;
    int col0 = blockIdx.y * 128;  // group g = blockIdx.y
    int kmax = (3 + 2 * (int)blockIdx.y) * 512;   // 1536/2560/3584/4608
    int lane = tid & 63, wave = tid >> 6;
    int wr = (wave >> 1) * 64, wc = (wave & 1) * 64;
    int l15 = lane & 15, lg = lane >> 4;
    f32x4 acc[4][4] = {};
    for (int k0 = 0; k0 < kmax; k0 += 64) {
        int j = k0 >> 9, c0 = k0 & 511;  // 64 | 512 so tap j constant per chunk
        for (int ci = tid; ci < 1024; ci += 256) {
            int rr = ci >> 3, kc = (ci & 7) * 8;
            *(s16x8*)(&As[rr][kc]) =
                *(const s16x8*)(R + ((size_t)(b * TP) + t0 + rr + j) * 512 + c0 + kc);
            *(s16x8*)(&Bs[rr][kc]) = *(const s16x8*)(W + (size_t)(col0 + rr) * 4608 + k0 + kc);
        }
        __syncthreads();
#pragma unroll
        for (int kk = 0; kk < 64; kk += 32) {
            s16x8 af[4], bf[4];
#pragma unroll
            for (int m = 0; m < 4; ++m) af[m] = *(const s16x8*)(&As[wr + m * 16 + l15][kk + lg * 8]);
#pragma unroll
            for (int n = 0; n < 4; ++n) bf[n] = *(const s16x8*)(&Bs[wc + n * 16 + l15][kk + lg * 8]);
#pragma unroll
            for (int m = 0; m < 4; ++m)
#pragma unroll
                for (int n = 0; n < 4; ++n)
                    acc[m][n] = mfma_bf16(af[m], bf[n], acc[m][n]);
        }
        __syncthreads();
    }
    // fused max-pool epilogue (bias added later; max is monotone)
#pragma unroll
    for (int m = 0; m < 4; ++m)
#pragma unroll
        for (int n = 0; n < 4; ++n) {
            int f = col0 + wc + n * 16 + l15;
            int g = f >> 7;
            int tmax = 509 - 2 * g;   // valid t <= 512 - k_g
            float v = -3.4e38f;
            int tb = t0 + wr + m * 16 + lg * 4;
#pragma unroll
            for (int i = 0; i < 4; ++i) {
                int t = tb + i;
                if (t <= tmax) v = fmaxf(v, acc[m][n][i]);
            }
            v = fmaxf(v, __shfl_xor(v, 16));
            v = fmaxf(v, __shfl_xor(v, 32));
            if (lane < 16) atomicMax(&pooled[b * 512 + f], mapf(v));
        }
}

// ---------- pooled -> fc1 -> fc2 -> sigmoid ----------
__global__ __launch_bounds__(256) void fc_k(
    const unsigned int* __restrict__ pooled,
    const float* __restrict__ cb3, const float* __restrict__ cb5,
    const float* __restrict__ cb7, const float* __restrict__ cb9,
    const float* __restrict__ fc1_w, const float* __restrict__ fc1_b,
    const float* __restrict__ fc2_w, const float* __restrict__ fc2_b,
    float* __restrict__ out)
{
    int b = blockIdx.x, tid = threadIdx.x;
    __shared__ float x[512];
    __shared__ float y[256];
    for (int i = tid; i < 512; i += 256) {
        unsigned int u = pooled[b * 512 + i];
        unsigned int bits = (u & 0x80000000u) ? (u & 0x7FFFFFFFu) : ~u;
        union { unsigned int uu; float f; } v; v.uu = bits;
        int g = i >> 7;
        const float* cb = (g == 0) ? cb3 : ((g == 1) ? cb5 : ((g == 2) ? cb7 : cb9));
        x[i] = v.f + cb[i & 127];
    }
    __syncthreads();
    float a = fc1_b[tid];
    const float* wrow = fc1_w + (size_t)tid * 512;
    for (int k = 0; k < 512; k += 4)
        a += x[k] * wrow[k] + x[k + 1] * wrow[k + 1] + x[k + 2] * wrow[k + 2] + x[k + 3] * wrow[k + 3];
    y[tid] = fmaxf(a, 0.f);
    __syncthreads();
    if (tid < 64) {
        float p = 0.f;
        for (int k = tid; k < 256; k += 64) p += y[k] * fc2_w[k];
#pragma unroll
        for (int o = 32; o > 0; o >>= 1) p += __shfl_down(p, o);
        if (tid == 0) out[b] = 1.f / (1.f + __expf(-(p + fc2_b[0])));
    }
}

// ---------- host ----------
extern "C" void kernel_launch(void* const* d_in, const int* in_sizes, int n_in,
                              void* d_out, int out_size, void* d_ws, size_t ws_size,
                              hipStream_t stream)
{
    const int*   tokens  = (const int*)d_in[0];
    const int*   lengths = (const int*)d_in[1];
    const float* emb     = (const float*)d_in[2];
    const float* Wih_f   = (const float*)d_in[3];
    const float* Whh_f   = (const float*)d_in[4];
    const float* bih_f   = (const float*)d_in[5];
    const float* bhh_f   = (const float*)d_in[6];
    const float* Wih_b   = (const float*)d_in[7];
    const float* Whh_b   = (const float*)d_in[8];
    const float* bih_b   = (const float*)d_in[9];
    const float* bhh_b   = (const float*)d_in[10];
    const float* attn_w  = (const float*)d_in[11];
    const float* cw3 = (const float*)d_in[13]; const float* cb3 = (const float*)d_in[14];
    const float* cw5 = (const float*)d_in[15]; const float* cb5 = (const float*)d_in[16];
    const float* cw7 = (const float*)d_in[17]; const float* cb7 = (const float*)d_in[18];
    const float* cw9 = (const float*)d_in[19]; const float* cb9 = (const float*)d_in[20];
    const float* fc1_w = (const float*)d_in[21]; const float* fc1_b = (const float*)d_in[22];
    const float* fc2_w = (const float*)d_in[23]; const float* fc2_b = (const float*)d_in[24];
    float* out = (float*)d_out;

    char* ws = (char*)d_ws;
    // Workspace layout (~217 MB). r reuses A_f/A_b (A dead after xg GEMMs);
    // scale_ws reuses Wb_f (dead after xg GEMMs).
    unsigned short* A_f    = (unsigned short*)(ws + 0);
    unsigned short* A_b    = (unsigned short*)(ws + 20971520);
    unsigned short* r      = (unsigned short*)(ws + 0);           // overlaps A (time-disjoint)
    unsigned short* Wb_f   = (unsigned short*)(ws + 41943040);
    float*          scale_ws = (float*)(ws + 41943040);           // overlaps Wb_f (time-disjoint)
    unsigned short* Wb_b   = (unsigned short*)(ws + 42598400);
    unsigned short* Whhb_f = (unsigned short*)(ws + 43253760);
    unsigned short* Whhb_b = (unsigned short*)(ws + 43778048);
    float*          bias_f = (float*)(ws + 44302336);
    float*          bias_b = (float*)(ws + 44306432);
    unsigned short* Wcat   = (unsigned short*)(ws + 44310528);
    unsigned int*   pooled = (unsigned int*)(ws + 49029120);
    unsigned short* xg_f   = (unsigned short*)(ws + 49160192);
    unsigned short* xg_b   = (unsigned short*)(ws + 116269056);
    unsigned short* hs     = (unsigned short*)(ws + 183377920);
    // total = 216932352 bytes

    prep_all<<<(6195200 + 255) / 256, 256, 0, stream>>>(
        Wih_f, Wih_b, Whh_f, Whh_b, bih_f, bhh_f, bih_b, bhh_b,
        cw3, cw5, cw7, cw9, tokens, lengths, emb,
        Wb_f, Wb_b, Whhb_f, Whhb_b, bias_f, bias_b, Wcat, pooled, A_f, A_b);

    gemm_xg_k<<<dim3(256, 8), 256, 0, stream>>>(A_f, Wb_f, bias_f, xg_f);
    gemm_xg_k<<<dim3(256, 8), 256, 0, stream>>>(A_b, Wb_b, bias_b, xg_b);

    lstm_rec<<<8, 512, 0, stream>>>(xg_f, xg_b, Whhb_f, Whhb_b, lengths, hs);

    zero_r<<<(262144 + 255) / 256, 256, 0, stream>>>(r);   // after GEMMs (r overlaps A)
    attn_e<<<64, 256, 0, stream>>>(hs, lengths, attn_w, scale_ws);
    attn_scale<<<8192, 256, 0, stream>>>(hs, scale_ws, r);

    gemm_conv<<<dim3(256, 4), 256, 0, stream>>>(r, Wcat, pooled);

    fc_k<<<64, 256, 0, stream>>>(pooled, cb3, cb5, cb7, cb9,
                                 fc1_w, fc1_b, fc2_w, fc2_b, out);
}

// Round 18
// 1864.416 us; speedup vs baseline: 1.1618x; 1.0171x over previous
//
#include <hip/hip_runtime.h>
#include <stdint.h>

// ---------- types / helpers ----------
typedef __attribute__((ext_vector_type(4))) float f32x4;
typedef __attribute__((ext_vector_type(8))) short s16x8;
typedef __attribute__((ext_vector_type(4))) unsigned short us4;

__device__ __forceinline__ float b2f(unsigned short h) {
    union { unsigned int u; float f; } v; v.u = ((unsigned int)h) << 16; return v.f;
}
__device__ __forceinline__ unsigned short f2b(float f) {
    union { float f; unsigned int u; } v; v.f = f;
    unsigned int u = v.u;
    unsigned int r = (u + 0x7FFFu + ((u >> 16) & 1u)) >> 16;
    return (unsigned short)r;
}
__device__ __forceinline__ f32x4 mfma_bf16(s16x8 a, s16x8 b, f32x4 c) {
    return __builtin_amdgcn_mfma_f32_16x16x32_bf16(a, b, c, 0, 0, 0);
}
// Fast reciprocal: v_rcp_f32 (~1 ulp) instead of the IEEE div sequence.
// R11: this alone was lstm 2174->1552us. Error budget ~1e-2, rcp err ~1e-7.
__device__ __forceinline__ float fast_rcp(float x) {
    return __builtin_amdgcn_rcpf(x);
}
__device__ __forceinline__ float sigm(float x) {
    return fast_rcp(1.f + __expf(-x));
}
__device__ __forceinline__ float tanh_ap(float x) {
    float e = __expf(2.f * x);
    return 1.f - 2.f * fast_rcp(e + 1.f);
}
__device__ __forceinline__ unsigned int mapf(float f) {   // order-preserving f32->u32
    union { float f; unsigned int u; } v; v.f = f;
    return (v.u & 0x80000000u) ? ~v.u : (v.u | 0x80000000u);
}
// async global->LDS, 16B per lane; LDS dest must be wave-uniform (HW adds lane*16)
__device__ __forceinline__ void gl_lds16(const unsigned short* g, unsigned short* l) {
    __builtin_amdgcn_global_load_lds(
        (const __attribute__((address_space(1))) unsigned int*)g,
        (__attribute__((address_space(3))) unsigned int*)l, 16, 0, 0);
}

// Problem constants
#define TT 512
#define BB 64
#define EE 300
#define EPAD 320
#define HH 256
#define G4 1024
#define TP 520   // padded time for conv windows

// ---------- merged prep: weight conversions + conv weights + pool init + A gather ----
__global__ void prep_all(const float* __restrict__ Wih_f, const float* __restrict__ Wih_b,
                         const float* __restrict__ Whh_f, const float* __restrict__ Whh_b,
                         const float* __restrict__ bih_f, const float* __restrict__ bhh_f,
                         const float* __restrict__ bih_b, const float* __restrict__ bhh_b,
                         const float* __restrict__ w3, const float* __restrict__ w5,
                         const float* __restrict__ w7, const float* __restrict__ w9,
                         const int* __restrict__ tokens, const int* __restrict__ lengths,
                         const float* __restrict__ emb,
                         unsigned short* __restrict__ Wb_f, unsigned short* __restrict__ Wb_b,
                         unsigned short* __restrict__ Whhb_f, unsigned short* __restrict__ Whhb_b,
                         float* __restrict__ bias_f, float* __restrict__ bias_b,
                         unsigned short* __restrict__ Wcat, unsigned int* __restrict__ pooled,
                         unsigned short* __restrict__ A_f, unsigned short* __restrict__ A_b)
{
    int idx = blockIdx.x * 256 + threadIdx.x;
    if (idx < 327680) {
        int n = idx / EPAD, k = idx % EPAD;
        Wb_f[idx] = f2b(k < EE ? Wih_f[n * EE + k] : 0.f);
    } else if (idx < 655360) {
        int i = idx - 327680; int n = i / EPAD, k = i % EPAD;
        Wb_b[i] = f2b(k < EE ? Wih_b[n * EE + k] : 0.f);
    } else if (idx < 917504) {
        int i = idx - 655360; Whhb_f[i] = f2b(Whh_f[i]);
    } else if (idx < 1179648) {
        int i = idx - 917504; Whhb_b[i] = f2b(Whh_b[i]);
    } else if (idx < 1180672) {
        int i = idx - 1179648; bias_f[i] = bih_f[i] + bhh_f[i];
    } else if (idx < 1181696) {
        int i = idx - 1180672; bias_b[i] = bih_b[i] + bhh_b[i];
    } else if (idx < 3540992) {
        int i = idx - 1181696;
        int f = i / 4608, kk = i - f * 4608;
        int j = kk >> 9, cc = kk & 511;
        int g = f >> 7, fl = f & 127;
        int kw = 3 + 2 * g;
        const float* src = (g == 0) ? w3 : ((g == 1) ? w5 : ((g == 2) ? w7 : w9));
        float v = (j < kw) ? src[((size_t)fl * 512 + cc) * kw + j] : 0.f;
        Wcat[i] = f2b(v);
    } else if (idx < 3573760) {
        pooled[idx - 3540992] = 0x007FFFFFu;   // mapf(-inf)
    } else if (idx < 6195200) {
        int i = idx - 3573760;
        const int per = 32768 * 40;
        int dirc = i >= per;
        int rem = dirc ? i - per : i;
        int row = rem / 40, kc = (rem - row * 40) * 8;
        int t = row >> 6, b = row & 63;
        int ts = t;
        if (dirc) { int len = lengths[b]; ts = (t < len) ? (len - 1 - t) : t; }
        int tok = tokens[b * TT + ts];
        const float* ep = emb + (size_t)tok * EE;
        unsigned short* dst = (dirc ? A_b : A_f) + (size_t)row * EPAD + kc;
#pragma unroll
        for (int j2 = 0; j2 < 8; ++j2) {
            int e = kc + j2;
            dst[j2] = f2b(e < EE ? ep[e] : 0.f);
        }
    }
}

__global__ void zero_r(unsigned short* __restrict__ r) {
    int idx = blockIdx.x * 256 + threadIdx.x;   // 64 batches * 8 rows * 512 ch
    if (idx >= 64 * 8 * 512) return;
    int b = idx >> 12;
    int rem = idx & 4095;
    r[((size_t)b * TP + 512) * 512 + rem] = 0;
}

// ---------- GEMM: xg = A[M,320] * B[1024,320]^T(K-major) + bias -> bf16 ----------
// Output layout: xg[t][grp4][col1024][b16] (us4 packed over batch) for coalesced lstm reads
__global__ __launch_bounds__(256) void gemm_xg_k(
    const unsigned short* __restrict__ A, const unsigned short* __restrict__ Bw,
    const float* __restrict__ bias, unsigned short* __restrict__ C)
{
    __shared__ unsigned short As[128][72];
    __shared__ unsigned short Bs[128][72];
    const int KA = EPAD;
    int tid = threadIdx.x;
    int row0 = blockIdx.x * 128, col0 = blockIdx.y * 128;
    int lane = tid & 63, wave = tid >> 6;
    int wr = (wave >> 1) * 64, wc = (wave & 1) * 64;
    int l15 = lane & 15, lg = lane >> 4;
    f32x4 acc[4][4] = {};
    for (int k0 = 0; k0 < KA; k0 += 64) {
        for (int ci = tid; ci < 1024; ci += 256) {
            int rr = ci >> 3, kc = (ci & 7) * 8;
            *(s16x8*)(&As[rr][kc]) = *(const s16x8*)(A + (size_t)(row0 + rr) * KA + k0 + kc);
            *(s16x8*)(&Bs[rr][kc]) = *(const s16x8*)(Bw + (size_t)(col0 + rr) * KA + k0 + kc);
        }
        __syncthreads();
#pragma unroll
        for (int kk = 0; kk < 64; kk += 32) {
            s16x8 af[4], bf[4];
#pragma unroll
            for (int m = 0; m < 4; ++m) af[m] = *(const s16x8*)(&As[wr + m * 16 + l15][kk + lg * 8]);
#pragma unroll
            for (int n = 0; n < 4; ++n) bf[n] = *(const s16x8*)(&Bs[wc + n * 16 + l15][kk + lg * 8]);
#pragma unroll
            for (int m = 0; m < 4; ++m)
#pragma unroll
                for (int n = 0; n < 4; ++n)
                    acc[m][n] = mfma_bf16(af[m], bf[n], acc[m][n]);
        }
        __syncthreads();
    }
    // epilogue: rows are (t*64 + batch); within this tile batch = m*16 + lg*4 + i, grp = m
    int t = (row0 + wr) >> 6;
#pragma unroll
    for (int m = 0; m < 4; ++m)
#pragma unroll
        for (int n = 0; n < 4; ++n) {
            int ccol = col0 + wc + n * 16 + l15;
            float bb = bias[ccol];
            us4 pk;
#pragma unroll
            for (int i = 0; i < 4; ++i) pk[i] = f2b(acc[m][n][i] + bb);
            size_t us4_idx = (((size_t)t * 4 + m) * 1024 + ccol) * 4 + lg;
            *(us4*)(C + us4_idx * 4) = pk;
        }
}

// ---------- LSTM recurrence: persistent; ONE barrier/step via h_a double-buffer ----
// R15 configuration (1485us anchor): R12 schedule, wl2a issued after the barrier.
// FROZEN: every epilogue/schedule rewrite (R6/R8/R9/R10/R13/R16) regressed.
#define LSTM_STEP(S, XCUR, XNXT, HC, HW)                                          \
{                                                                                 \
    f32x4 acc[8];                                                                 \
    _Pragma("unroll")                                                             \
    for (int ct = 0; ct < 8; ++ct) {                                              \
        f32x4 a;                                                                  \
        _Pragma("unroll")                                                         \
        for (int i = 0; i < 4; ++i) a[i] = b2f(XCUR[ct][i]);                      \
        acc[ct] = a;                                                              \
    }                                                                             \
    __syncthreads();   /* single barrier: prev-step h writes visible */           \
    _Pragma("unroll")                                                             \
    for (int ct = 0; ct < 8; ++ct)                                                \
        wl2a[ct] = *(const s16x8*)(wbase + coff[ct] + 6 * 32);                    \
    s16x8 af[8];                                                                  \
    _Pragma("unroll")                                                             \
    for (int kt = 0; kt < 8; ++kt) af[kt] = *(const s16x8*)((HC) + kt * 32);      \
    _Pragma("unroll")                                                             \
    for (int kt = 0; kt < 4; ++kt)                                                \
        _Pragma("unroll")                                                         \
        for (int ct = 0; ct < 8; ++ct)                                            \
            acc[ct] = mfma_bf16(af[kt], wreg[ct * 4 + kt], acc[ct]);              \
    _Pragma("unroll")                                                             \
    for (int ct = 0; ct < 8; ++ct)                                                \
        wl2b[ct] = *(const s16x8*)(wbase + coff[ct] + 7 * 32);                    \
    _Pragma("unroll")                                                             \
    for (int ktl = 0; ktl < 2; ++ktl)                                             \
        _Pragma("unroll")                                                         \
        for (int ct = 0; ct < 8; ++ct)                                            \
            acc[ct] = mfma_bf16(af[4 + ktl], w_lds[wave][ktl][ct][lane], acc[ct]);\
    {                                                                             \
        int sp1 = (S) + 1; if (sp1 > 511) sp1 = 511;                              \
        const unsigned short* xs = xbase + (size_t)sp1 * 65536;                   \
        XNXT[0] = *(const us4*)(xs);                                              \
        XNXT[1] = *(const us4*)(xs + 256);                                        \
        XNXT[2] = *(const us4*)(xs + 4096);                                       \
        XNXT[3] = *(const us4*)(xs + 4352);                                       \
        XNXT[4] = *(const us4*)(xs + 8192);                                       \
        XNXT[5] = *(const us4*)(xs + 8448);                                       \
        XNXT[6] = *(const us4*)(xs + 12288);                                      \
        XNXT[7] = *(const us4*)(xs + 12544);                                      \
    }                                                                             \
    _Pragma("unroll")                                                             \
    for (int ct = 0; ct < 8; ++ct) acc[ct] = mfma_bf16(af[6], wl2a[ct], acc[ct]); \
    _Pragma("unroll")                                                             \
    for (int ct = 0; ct < 8; ++ct) acc[ct] = mfma_bf16(af[7], wl2b[ct], acc[ct]); \
    _Pragma("unroll")                                                             \
    for (int h2 = 0; h2 < 2; ++h2)                                                \
    _Pragma("unroll")                                                             \
    for (int i = 0; i < 4; ++i) {                                                 \
        int bi = lg * 4 + i;                                                      \
        int u = wave * 32 + h2 * 16 + l15;                                        \
        float gi = acc[0 + h2][i], gf = acc[2 + h2][i];                           \
        float gg = acc[4 + h2][i], go = acc[6 + h2][i];                           \
        float si = sigm(gi), sf = sigm(gf), so = sigm(go);                        \
        float tg = tanh_ap(gg);                                                   \
        int q = h2 * 4 + i;                                                       \
        float cc = sf * c[q] + si * tg; c[q] = cc;                                \
        float hh = so * tanh_ap(cc);                                              \
        (HW)[bi][u] = f2b(hh);                                                    \
        int len = len_s[bi];                                                      \
        if ((S) < len) {                                                          \
            int t_out = dir ? (len - 1 - (S)) : (S);                              \
            hs[((size_t)t_out * 64 + (grp * 16 + bi)) * 512 + dir * 256 + u] = f2b(hh); \
        }                                                                         \
    }                                                                             \
}

__global__ __launch_bounds__(512, 2) void lstm_rec(
    const unsigned short* __restrict__ xg_f, const unsigned short* __restrict__ xg_b,
    const unsigned short* __restrict__ Whh_fb, const unsigned short* __restrict__ Whh_bb,
    const int* __restrict__ lengths, unsigned short* __restrict__ hs)
{
    int wg = blockIdx.x;
    int dir = wg >> 2, grp = wg & 3;
    const unsigned short* XG = dir ? xg_b : xg_f;     // [t][grp][1024 col][16 b]
    const unsigned short* WH = dir ? Whh_bb : Whh_fb; // [1024 col][256 k]
    int tid = threadIdx.x, lane = tid & 63, wave = tid >> 6;
    int l15 = lane & 15, lg = lane >> 4;

    __shared__ unsigned short h_a[2][16][264];   // DOUBLE-buffered hidden state
    __shared__ s16x8 w_lds[8][2][8][64];         // kt4-5, per-wave private, 128 KB
    __shared__ int len_s[16];
    __shared__ int ml_s;

    if (tid < 16) len_s[tid] = lengths[grp * 16 + tid];
    for (int i = tid; i < 2 * 16 * 264; i += 512) (&h_a[0][0][0])[i] = 0;
    __syncthreads();
    if (tid == 0) {
        int m = 0;
        for (int i = 0; i < 16; ++i) m = max(m, len_s[i]);
        ml_s = m;
    }

    // per-thread weight base + per-ct col offsets (units: unsigned short)
    const unsigned short* wbase = WH + (size_t)(wave * 32 + l15) * HH + lg * 8;
    const int coff[8] = {0, 16 * HH, 256 * HH, 272 * HH, 512 * HH, 528 * HH, 768 * HH, 784 * HH};

    // persistent weights: kt0-3 regs, kt4-5 LDS
    s16x8 wreg[32];
#pragma unroll
    for (int ct = 0; ct < 8; ++ct) {
#pragma unroll
        for (int kt = 0; kt < 4; ++kt)
            wreg[ct * 4 + kt] = *(const s16x8*)(wbase + coff[ct] + kt * 32);
#pragma unroll
        for (int ktl = 0; ktl < 2; ++ktl)
            w_lds[wave][ktl][ct][lane] = *(const s16x8*)(wbase + coff[ct] + (4 + ktl) * 32);
    }
    __syncthreads();   // w_lds + ml_s ready
    int maxlen = ml_s;

    float c[8];
#pragma unroll
    for (int q = 0; q < 8; ++q) c[q] = 0.f;

    const unsigned short* hc0 = &h_a[0][l15][lg * 8];
    const unsigned short* hc1 = &h_a[1][l15][lg * 8];
    // xg base for this thread (us units); per-s stride 65536
    const unsigned short* xbase = XG + (size_t)grp * 16384 + (wave * 32 + l15) * 16 + lg * 4;

    s16x8 wl2a[8], wl2b[8];
    us4 xga[8], xgb[8];
    {
        const unsigned short* xs = xbase;
        xga[0] = *(const us4*)(xs);         xga[1] = *(const us4*)(xs + 256);
        xga[2] = *(const us4*)(xs + 4096);  xga[3] = *(const us4*)(xs + 4352);
        xga[4] = *(const us4*)(xs + 8192);  xga[5] = *(const us4*)(xs + 8448);
        xga[6] = *(const us4*)(xs + 12288); xga[7] = *(const us4*)(xs + 12544);
    }

    int s = 0;
    for (; s + 1 < maxlen; s += 2) {
        LSTM_STEP(s, xga, xgb, hc0, h_a[1])
        LSTM_STEP(s + 1, xgb, xga, hc1, h_a[0])
    }
    if (s < maxlen) {
        LSTM_STEP(s, xga, xgb, hc0, h_a[1])
    }
}

// ---------- attention part 1: per-(b,t) softmax scale -> scale_ws ----------
__global__ __launch_bounds__(256) void attn_e(
    const unsigned short* __restrict__ hs, const int* __restrict__ lengths,
    const float* __restrict__ attn_w, float* __restrict__ scale_ws)
{
    int b = blockIdx.x, tid = threadIdx.x;
    __shared__ float aw[512];
    __shared__ float e_s[512];
    __shared__ float red[4];
    __shared__ float ssum;
    for (int i = tid; i < 512; i += 256) aw[i] = attn_w[i];
    int len = lengths[b];
    __syncthreads();
    for (int t = tid; t < 512; t += 256) {
        float e = 0.f;
        if (t < len) {
            const unsigned short* hp = hs + ((size_t)t * 64 + b) * 512;
            float u = 0.f;
            for (int c8 = 0; c8 < 64; ++c8) {
                s16x8 hv = *(const s16x8*)(hp + c8 * 8);
#pragma unroll
                for (int j = 0; j < 8; ++j)
                    u += tanh_ap(b2f((unsigned short)hv[j])) * aw[c8 * 8 + j];
            }
            e = __expf(u);   // attn_b cancels in normalization
        }
        e_s[t] = e;
    }
    __syncthreads();
    float p = e_s[tid] + e_s[tid + 256];
#pragma unroll
    for (int o = 32; o > 0; o >>= 1) p += __shfl_down(p, o);
    if ((tid & 63) == 0) red[tid >> 6] = p;
    __syncthreads();
    if (tid == 0) ssum = red[0] + red[1] + red[2] + red[3];
    __syncthreads();
    float inv = fast_rcp(ssum);
    for (int t = tid; t < 512; t += 256)
        scale_ws[b * 512 + t] = e_s[t] * inv;
}

// ---------- attention part 2: r[b][t][c] = hs[t][b][c] * scale (coalesced) ------
// One wave per (b,t) row; 8192 blocks x 4 waves = 32768 rows.
__global__ __launch_bounds__(256) void attn_scale(
    const unsigned short* __restrict__ hs, const float* __restrict__ scale_ws,
    unsigned short* __restrict__ r)
{
    int row = blockIdx.x * 4 + (threadIdx.x >> 6);   // b*512 + t
    int lane = threadIdx.x & 63;
    int b = row >> 9, t = row & 511;
    float sc = scale_ws[row];
    s16x8 hv = *(const s16x8*)(hs + ((size_t)t * 64 + b) * 512 + lane * 8);
    s16x8 ov;
#pragma unroll
    for (int j = 0; j < 8; ++j)
        ov[j] = (short)f2b(b2f((unsigned short)hv[j]) * sc);
    *(s16x8*)(r + ((size_t)b * TP + t) * 512 + lane * 8) = ov;
}

// ---------- conv as implicit-im2col GEMM + fused max-pool ----------
// K-trimmed (R7).  R18: staging via global_load_lds width=16 (async DMA, no VGPR
// round-trip; m151: +35% vs reg-staging at this tile).  LDS is LINEAR [128][64]
// (gload_lds needs contiguous dest = wave-uniform base + lane*16B; rule #21:
// linear dest + per-lane global src, no swizzle on either side).
__global__ __launch_bounds__(256) void gemm_conv(
    const unsigned short* __restrict__ R, const unsigned short* __restrict__ W,
    unsigned int* __restrict__ pooled)
{
    __shared__ unsigned short As[128 * 64];
    __shared__ unsigned short Bs[128 * 64];
    int tid = threadIdx.x;
    int bm = blockIdx.x;          // 0..255
    int b = bm >> 2;
    int t0 = (bm & 3) * 128;
    int col0 = blockIdx.y * 128;  // group g = blockIdx.y
    int kmax = (3 + 2 * (int)blockIdx.y) * 512;   // 1536/2560/3584/4608
    int lane = tid & 63, wave = tid >> 6;
    int wr = (wave >> 1) * 64, wc = (wave & 1) * 64;
    int l15 = lane & 15, lg = lane >> 4;
    int lrow = lane >> 3, lcol = (lane & 7) * 8;  // staging: lane covers row+lrow, col lcol
    f32x4 acc[4][4] = {};
    for (int k0 = 0; k0 < kmax; k0 += 64) {
        int j = k0 >> 9, c0 = k0 & 511;  // 64 | 512 so tap j constant per chunk
        // async stage: each wave fills rows [wave*32, wave*32+32) in 4 issues of 8 rows
        const unsigned short* asrc = R + ((size_t)(b * TP) + t0 + j) * 512 + c0;
        const unsigned short* bsrc = W + (size_t)col0 * 4608 + k0;
#pragma unroll
        for (int q = 0; q < 4; ++q) {
            int row = wave * 32 + q * 8;
            gl_lds16(asrc + (size_t)(row + lrow) * 512 + lcol, &As[row * 64]);
            gl_lds16(bsrc + (size_t)(row + lrow) * 4608 + lcol, &Bs[row * 64]);
        }
        __syncthreads();   // drains vmcnt -> gload_lds complete
#pragma unroll
        for (int kk = 0; kk < 64; kk += 32) {
            s16x8 af[4], bf[4];
#pragma unroll
            for (int m = 0; m < 4; ++m) af[m] = *(const s16x8*)(&As[(wr + m * 16 + l15) * 64 + kk + lg * 8]);
#pragma unroll
            for (int n = 0; n < 4; ++n) bf[n] = *(const s16x8*)(&Bs[(wc + n * 16 + l15) * 64 + kk + lg * 8]);
#pragma unroll
            for (int m = 0; m < 4; ++m)
#pragma unroll
                for (int n = 0; n < 4; ++n)
                    acc[m][n] = mfma_bf16(af[m], bf[n], acc[m][n]);
        }
        __syncthreads();
    }
    // fused max-pool epilogue (bias added later; max is monotone)
#pragma unroll
    for (int m = 0; m < 4; ++m)
#pragma unroll
        for (int n = 0; n < 4; ++n) {
            int f = col0 + wc + n * 16 + l15;
            int g = f >> 7;
            int tmax = 509 - 2 * g;   // valid t <= 512 - k_g
            float v = -3.4e38f;
            int tb = t0 + wr + m * 16 + lg * 4;
#pragma unroll
            for (int i = 0; i < 4; ++i) {
                int t = tb + i;
                if (t <= tmax) v = fmaxf(v, acc[m][n][i]);
            }
            v = fmaxf(v, __shfl_xor(v, 16));
            v = fmaxf(v, __shfl_xor(v, 32));
            if (lane < 16) atomicMax(&pooled[b * 512 + f], mapf(v));
        }
}

// ---------- pooled -> fc1 -> fc2 -> sigmoid ----------
__global__ __launch_bounds__(256) void fc_k(
    const unsigned int* __restrict__ pooled,
    const float* __restrict__ cb3, const float* __restrict__ cb5,
    const float* __restrict__ cb7, const float* __restrict__ cb9,
    const float* __restrict__ fc1_w, const float* __restrict__ fc1_b,
    const float* __restrict__ fc2_w, const float* __restrict__ fc2_b,
    float* __restrict__ out)
{
    int b = blockIdx.x, tid = threadIdx.x;
    __shared__ float x[512];
    __shared__ float y[256];
    for (int i = tid; i < 512; i += 256) {
        unsigned int u = pooled[b * 512 + i];
        unsigned int bits = (u & 0x80000000u) ? (u & 0x7FFFFFFFu) : ~u;
        union { unsigned int uu; float f; } v; v.uu = bits;
        int g = i >> 7;
        const float* cb = (g == 0) ? cb3 : ((g == 1) ? cb5 : ((g == 2) ? cb7 : cb9));
        x[i] = v.f + cb[i & 127];
    }
    __syncthreads();
    float a = fc1_b[tid];
    const float* wrow = fc1_w + (size_t)tid * 512;
    for (int k = 0; k < 512; k += 4)
        a += x[k] * wrow[k] + x[k + 1] * wrow[k + 1] + x[k + 2] * wrow[k + 2] + x[k + 3] * wrow[k + 3];
    y[tid] = fmaxf(a, 0.f);
    __syncthreads();
    if (tid < 64) {
        float p = 0.f;
        for (int k = tid; k < 256; k += 64) p += y[k] * fc2_w[k];
#pragma unroll
        for (int o = 32; o > 0; o >>= 1) p += __shfl_down(p, o);
        if (tid == 0) out[b] = 1.f / (1.f + __expf(-(p + fc2_b[0])));
    }
}

// ---------- host ----------
extern "C" void kernel_launch(void* const* d_in, const int* in_sizes, int n_in,
                              void* d_out, int out_size, void* d_ws, size_t ws_size,
                              hipStream_t stream)
{
    const int*   tokens  = (const int*)d_in[0];
    const int*   lengths = (const int*)d_in[1];
    const float* emb     = (const float*)d_in[2];
    const float* Wih_f   = (const float*)d_in[3];
    const float* Whh_f   = (const float*)d_in[4];
    const float* bih_f   = (const float*)d_in[5];
    const float* bhh_f   = (const float*)d_in[6];
    const float* Wih_b   = (const float*)d_in[7];
    const float* Whh_b   = (const float*)d_in[8];
    const float* bih_b   = (const float*)d_in[9];
    const float* bhh_b   = (const float*)d_in[10];
    const float* attn_w  = (const float*)d_in[11];
    const float* cw3 = (const float*)d_in[13]; const float* cb3 = (const float*)d_in[14];
    const float* cw5 = (const float*)d_in[15]; const float* cb5 = (const float*)d_in[16];
    const float* cw7 = (const float*)d_in[17]; const float* cb7 = (const float*)d_in[18];
    const float* cw9 = (const float*)d_in[19]; const float* cb9 = (const float*)d_in[20];
    const float* fc1_w = (const float*)d_in[21]; const float* fc1_b = (const float*)d_in[22];
    const float* fc2_w = (const float*)d_in[23]; const float* fc2_b = (const float*)d_in[24];
    float* out = (float*)d_out;

    char* ws = (char*)d_ws;
    // Workspace layout (~217 MB). r reuses A_f/A_b (A dead after xg GEMMs);
    // scale_ws reuses Wb_f (dead after xg GEMMs).
    unsigned short* A_f    = (unsigned short*)(ws + 0);
    unsigned short* A_b    = (unsigned short*)(ws + 20971520);
    unsigned short* r      = (unsigned short*)(ws + 0);           // overlaps A (time-disjoint)
    unsigned short* Wb_f   = (unsigned short*)(ws + 41943040);
    float*          scale_ws = (float*)(ws + 41943040);           // overlaps Wb_f (time-disjoint)
    unsigned short* Wb_b   = (unsigned short*)(ws + 42598400);
    unsigned short* Whhb_f = (unsigned short*)(ws + 43253760);
    unsigned short* Whhb_b = (unsigned short*)(ws + 43778048);
    float*          bias_f = (float*)(ws + 44302336);
    float*          bias_b = (float*)(ws + 44306432);
    unsigned short* Wcat   = (unsigned short*)(ws + 44310528);
    unsigned int*   pooled = (unsigned int*)(ws + 49029120);
    unsigned short* xg_f   = (unsigned short*)(ws + 49160192);
    unsigned short* xg_b   = (unsigned short*)(ws + 116269056);
    unsigned short* hs     = (unsigned short*)(ws + 183377920);
    // total = 216932352 bytes

    prep_all<<<(6195200 + 255) / 256, 256, 0, stream>>>(
        Wih_f, Wih_b, Whh_f, Whh_b, bih_f, bhh_f, bih_b, bhh_b,
        cw3, cw5, cw7, cw9, tokens, lengths, emb,
        Wb_f, Wb_b, Whhb_f, Whhb_b, bias_f, bias_b, Wcat, pooled, A_f, A_b);

    gemm_xg_k<<<dim3(256, 8), 256, 0, stream>>>(A_f, Wb_f, bias_f, xg_f);
    gemm_xg_k<<<dim3(256, 8), 256, 0, stream>>>(A_b, Wb_b, bias_b, xg_b);

    lstm_rec<<<8, 512, 0, stream>>>(xg_f, xg_b, Whhb_f, Whhb_b, lengths, hs);

    zero_r<<<(262144 + 255) / 256, 256, 0, stream>>>(r);   // after GEMMs (r overlaps A)
    attn_e<<<64, 256, 0, stream>>>(hs, lengths, attn_w, scale_ws);
    attn_scale<<<8192, 256, 0, stream>>>(hs, scale_ws, r);

    gemm_conv<<<dim3(256, 4), 256, 0, stream>>>(r, Wcat, pooled);

    fc_k<<<64, 256, 0, stream>>>(pooled, cb3, cb5, cb7, cb9,
                                 fc1_w, fc1_b, fc2_w, fc2_b, out);
}